// Round 10
// baseline (80.585 us; speedup 1.0000x reference)
//
#include <hip/hip_runtime.h>
#include <hip/hip_bf16.h>
#include <math.h>

#define G 4
#define T 2048
#define H 1024
#define E 8
#define NBUK 2048  // 11-bit buckets (key>>53)
#define SELB 32    // K2 select blocks (one per g,e)
#define K1B 512    // K1 blocks (4 waves x 4 grid-stride iters)
#define K2B 256    // K2 total blocks
#define K3B 256    // K3 total blocks
#define SCB 12     // K3 scatter blocks (12*1024 == G*E*384)

typedef float f4 __attribute__((ext_vector_type(4)));
typedef unsigned long long u64;

// ---------------------------------------------------------------------------
// R10 theory: measured dur tracks TOTAL WORKGROUP COUNT (~4-6ns/wg dispatch),
// not per-kernel work. 8672 wg (R9) -> 1024 wg here; all numeric paths are
// byte-identical to R9 (absmax=0.0).
// ---------------------------------------------------------------------------

// K1: logits+softmax -> u64 keys. 512 blocks, 4 grid-stride token-waves per
// wave-slot. fp64 path + lane-parallel epilogue FROZEN (absmax=0.0 R2-R9).
__global__ __launch_bounds__(256) void k1_logits(
    const float* __restrict__ x, const float* __restrict__ W,
    const float* __restrict__ b, u64* __restrict__ keys,
    float* __restrict__ lse2) {
  int slot = (int)(blockIdx.x * 4 + (threadIdx.x >> 6));  // 0..2047
  int lane = (int)(threadIdx.x & 63);

  for (int wave = slot; wave < G * T; wave += K1B * 4) {
    const float* xr = x + (size_t)wave * H;
    double acc0 = 0, acc1 = 0, acc2 = 0, acc3 = 0;
    double acc4 = 0, acc5 = 0, acc6 = 0, acc7 = 0;
#pragma unroll
    for (int j = 0; j < 4; ++j) {
      int hbase = j * 256 + lane * 4;
      f4 xv = *(const f4*)(xr + hbase);
#pragma unroll
      for (int k = 0; k < 4; ++k) {
        const float* wr = W + (size_t)(hbase + k) * 8;
        f4 w0 = *(const f4*)(wr);
        f4 w1 = *(const f4*)(wr + 4);
        double xd = (double)xv[k];
        acc0 += xd * (double)w0[0];
        acc1 += xd * (double)w0[1];
        acc2 += xd * (double)w0[2];
        acc3 += xd * (double)w0[3];
        acc4 += xd * (double)w1[0];
        acc5 += xd * (double)w1[1];
        acc6 += xd * (double)w1[2];
        acc7 += xd * (double)w1[3];
      }
    }
#pragma unroll
    for (int off = 32; off >= 1; off >>= 1) {
      acc0 += __shfl_xor(acc0, off);
      acc1 += __shfl_xor(acc1, off);
      acc2 += __shfl_xor(acc2, off);
      acc3 += __shfl_xor(acc3, off);
      acc4 += __shfl_xor(acc4, off);
      acc5 += __shfl_xor(acc5, off);
      acc6 += __shfl_xor(acc6, off);
      acc7 += __shfl_xor(acc7, off);
    }
    double l0 = acc0 + (double)b[0], l1 = acc1 + (double)b[1];
    double l2 = acc2 + (double)b[2], l3 = acc3 + (double)b[3];
    double l4 = acc4 + (double)b[4], l5 = acc5 + (double)b[5];
    double l6 = acc6 + (double)b[6], l7 = acc7 + (double)b[7];
    double m = fmax(fmax(fmax(l0, l1), fmax(l2, l3)),
                    fmax(fmax(l4, l5), fmax(l6, l7)));
    double la = (lane & 1) ? l1 : l0;
    double lb = (lane & 1) ? l3 : l2;
    double lc = (lane & 1) ? l5 : l4;
    double ld = (lane & 1) ? l7 : l6;
    double le = (lane & 2) ? lb : la;
    double lf = (lane & 2) ? ld : lc;
    double lsel = (lane & 4) ? lf : le;

    double pe = exp(lsel - m);
    double s = pe;
    s += __shfl_xor(s, 1);
    s += __shfl_xor(s, 2);
    s += __shfl_xor(s, 4);  // bitwise == reference's add tree
    double inv = 1.0 / s;
    float pf = (float)(pe * inv);

    int g = wave >> 11;
    int t = wave & (T - 1);
    if (lane < 8) {
      keys[((size_t)g * 8 + lane) * T + t] =
          ((u64)__float_as_uint(pf) << 32) | (unsigned)(~t);
    }
    if (lane == 0) {
      double lse = m + log(s);
      lse2[wave] = (float)(lse * lse);
    }
  }
}

// K2: blocks [0,32) = exact radix-histogram select per (g,e) (proven R9);
// blocks [32,256) = zero dispatch half. No race: select writes only ws.
__global__ __launch_bounds__(1024) void k2_select_zero(
    const u64* __restrict__ keys, float* __restrict__ gate,
    int* __restrict__ idx, float* __restrict__ out, unsigned n4d, int max_cap,
    int ec) {
  unsigned bid = blockIdx.x;
  unsigned tid = threadIdx.x;

  if (bid >= SELB) {
    f4* outD = (f4*)out;
    f4 z = {0.0f, 0.0f, 0.0f, 0.0f};
    unsigned stride = (K2B - SELB) * 1024u;
    for (unsigned i = (bid - SELB) * 1024u + tid; i < n4d; i += stride)
      outD[i] = z;
    return;
  }

  __shared__ int hist[NBUK];
  __shared__ int sA[NBUK];
  __shared__ int sB[NBUK];
  __shared__ int cur[NBUK];
  __shared__ u64 srt[T];
  int ge = (int)bid;

  hist[tid] = 0;
  hist[tid + 1024] = 0;
  if (tid < (unsigned)max_cap) {
    gate[(size_t)ge * max_cap + tid] = 0.0f;
    idx[(size_t)ge * max_cap + tid] = -1;
  }
  __syncthreads();

  const u64* kcol = keys + (size_t)ge * T;
  u64 k0 = kcol[tid];
  u64 k1 = kcol[tid + 1024];
  int b0 = (int)(k0 >> 53);
  int b1 = (int)(k1 >> 53);
  atomicAdd(&hist[b0], 1);
  atomicAdd(&hist[b1], 1);
  __syncthreads();

  sA[tid] = hist[tid];
  sA[tid + 1024] = hist[tid + 1024];
  __syncthreads();
  int* src = sA;
  int* dst = sB;
  for (int s = 1; s < NBUK; s <<= 1) {
    for (int i = (int)tid; i < NBUK; i += 1024) {
      int v = src[i];
      if (i + s < NBUK) v += src[i + s];
      dst[i] = v;
    }
    __syncthreads();
    int* tmp = src;
    src = dst;
    dst = tmp;
  }
  for (int i = (int)tid; i < NBUK; i += 1024) cur[i] = src[i] - hist[i];
  __syncthreads();

  int p0 = atomicAdd(&cur[b0], 1);
  srt[p0] = k0;
  int p1 = atomicAdd(&cur[b1], 1);
  srt[p1] = k1;
  __syncthreads();

  const double factors[8] = {0.5, 0.75, 1.0, 1.0, 1.25, 1.25, 1.5, 1.5};
  int cap = (int)((double)ec * factors[ge & 7]);

  int o0 = src[b0] - hist[b0];
  if (o0 < cap) {
    int end = src[b0];
    int c = 0;
    for (int i = o0; i < end; ++i) c += (int)(srt[i] > k0);
    int r = o0 + c;
    if (r < cap) {
      gate[(size_t)ge * max_cap + r] = __uint_as_float((unsigned)(k0 >> 32));
      idx[(size_t)ge * max_cap + r] = (int)~(unsigned)k0;
    }
  }
  int o1 = src[b1] - hist[b1];
  if (o1 < cap) {
    int end = src[b1];
    int c = 0;
    for (int i = o1; i < end; ++i) c += (int)(srt[i] > k1);
    int r = o1 + c;
    if (r < cap) {
      gate[(size_t)ge * max_cap + r] = __uint_as_float((unsigned)(k1 >> 32));
      idx[(size_t)ge * max_cap + r] = (int)~(unsigned)k1;
    }
  }
}

// K3: block 0 = z-loss (256-thread shape kept bit-identical to R9);
// blocks [1,12] = scatter ones; [13,256) = combine broadcast-fill.
template <int MC4S>
__global__ __launch_bounds__(1024) void k3_scatter_combine(
    const float* __restrict__ gate, const int* __restrict__ idx,
    const float* __restrict__ lse2, float* __restrict__ out, unsigned n4d,
    unsigned mc4_rt, int max_cap) {
  const unsigned mc4 = MC4S ? (unsigned)MC4S : mc4_rt;
  unsigned tid = threadIdx.x;
  unsigned bid = blockIdx.x;

  if (bid == 0) {
    __shared__ double red[256];
    if (tid < 256) {
      double s = 0.0;
      for (int i = tid; i < G * T; i += 256) s += (double)lse2[i];
      red[tid] = s;
    }
    __syncthreads();
    for (int off = 128; off > 0; off >>= 1) {
      if ((int)tid < off) red[tid] += red[tid + off];
      __syncthreads();
    }
    if (tid == 0) {
      size_t ne = (size_t)n4d * 4;
      out[2 * ne] = 0.0f;                                   // auxiliary_loss
      out[2 * ne + 1] = (float)(red[0] / (double)(G * T));  // z_loss
    }
    return;
  }
  if (bid <= SCB) {
    unsigned s = (bid - 1) * 1024u + tid;
    if (s < (unsigned)(G * E) * (unsigned)max_cap) {
      unsigned ge = s / (unsigned)max_cap;
      unsigned c = s - ge * (unsigned)max_cap;
      int t = idx[s];
      if (t >= 0) out[((size_t)ge * T + t) * (unsigned)max_cap + c] = 1.0f;
    }
    return;
  }

  f4* outC = (f4*)out + n4d;
  const f4* gate4 = (const f4*)gate;
  unsigned fb = bid - 1 - SCB;
  unsigned nfb = K3B - 1 - SCB;
  unsigned stride = nfb * 1024u;
  for (unsigned i = fb * 1024u + tid; i < n4d; i += stride) {
    unsigned c4 = i % mc4;
    unsigned ge = (i / mc4) >> 11;
    outC[i] = gate4[ge * mc4 + c4];
  }
}

extern "C" void kernel_launch(void* const* d_in, const int* in_sizes, int n_in,
                              void* d_out, int out_size, void* d_ws,
                              size_t ws_size, hipStream_t stream) {
  const float* x = (const float*)d_in[0];
  const float* W = (const float*)d_in[1];
  const float* b = (const float*)d_in[2];

  // Derive max_cap from out_size: out = 2*G*E*T*max_cap + 2 scalars.
  long long body = (long long)out_size - 2;
  int max_cap = (int)(body / (2LL * G * E * T));  // 384 for ec=256
  if (max_cap <= 0) return;
  int ec = (2 * max_cap) / 3;  // max factor is 1.5

  u64* keys = (u64*)d_ws;                            // 32*2048 u64 = 512 KB
  float* lse2 = (float*)(keys + (size_t)G * E * T);  // 8192 floats
  float* gate = lse2 + (size_t)G * T;                // G*E*max_cap floats
  int* idx = (int*)(gate + (size_t)G * E * max_cap);

  unsigned n4d = (unsigned)((long long)G * E * T * max_cap / 4);  // per array

  k1_logits<<<K1B, 256, 0, stream>>>(x, W, b, keys, lse2);
  k2_select_zero<<<K2B, 1024, 0, stream>>>(keys, gate, idx, (float*)d_out,
                                           n4d, max_cap, ec);
  if (max_cap == 384) {
    k3_scatter_combine<96><<<K3B, 1024, 0, stream>>>(gate, idx, lse2,
                                                     (float*)d_out, n4d, 96u,
                                                     max_cap);
  } else {
    k3_scatter_combine<0><<<K3B, 1024, 0, stream>>>(
        gate, idx, lse2, (float*)d_out, n4d, (unsigned)(max_cap / 4), max_cap);
  }
}